// Round 1
// baseline (281.097 us; speedup 1.0000x reference)
//
#include <hip/hip_runtime.h>

typedef __attribute__((ext_vector_type(8))) short short8;
typedef __attribute__((ext_vector_type(4))) float f32x4;

__device__ __forceinline__ unsigned short f2bf(float f) {
  union { float f; unsigned u; } v; v.f = f;
  unsigned u = v.u + 0x7fffu + ((v.u >> 16) & 1u);
  return (unsigned short)(u >> 16);
}
__device__ __forceinline__ float bflo(unsigned u) {
  union { unsigned u; float f; } v; v.u = u << 16; return v.f;
}
__device__ __forceinline__ float bfhi(unsigned u) {
  union { unsigned u; float f; } v; v.u = u & 0xffff0000u; return v.f;
}
// XOR swizzle for [row][64] bf16 LDS tiles: spreads the 16-row fragment read
// across 8 distinct 16B slots (2-way residual = free per m136).
__device__ __forceinline__ int swz(int row, int col) {
  return row * 64 + (col ^ ((row & 7) << 3));
}

// ---------------- fp32 -> bf16 cast (vectorized, 8 elems/thread) ----------
__global__ __launch_bounds__(256) void cast_kernel(
    const float* __restrict__ in, unsigned short* __restrict__ out, int n8) {
  int i = blockIdx.x * 256 + threadIdx.x;
  if (i >= n8) return;
  const float* p = in + (size_t)i * 8;
  float4 f0 = *(const float4*)p;
  float4 f1 = *(const float4*)(p + 4);
  uint4 w;
  w.x = (unsigned)f2bf(f0.x) | ((unsigned)f2bf(f0.y) << 16);
  w.y = (unsigned)f2bf(f0.z) | ((unsigned)f2bf(f0.w) << 16);
  w.z = (unsigned)f2bf(f1.x) | ((unsigned)f2bf(f1.y) << 16);
  w.w = (unsigned)f2bf(f1.z) | ((unsigned)f2bf(f1.w) << 16);
  *(uint4*)(out + (size_t)i * 8) = w;
}

// ---------------- gemm_bt: C[MxN](bf16) = op(A[MxK] @ Bt[NxK]^T) ----------
// BM=64, BN=128, BK=64, 256 threads = 4 waves (2x2), per-wave 32x64.
// AFP32: A is fp32, converted to bf16 during LDS staging.
// BIAS_MODE: 0 none, 1 per-row, 2 per-col.  RELU: apply relu in epilogue.
template<int AFP32, int BIAS_MODE, int RELU>
__global__ __launch_bounds__(256, 2)
void gemm_bt(const void* __restrict__ Av, const unsigned short* __restrict__ Btv,
             unsigned short* __restrict__ Cv, const float* __restrict__ biasv,
             int K, int lda, int ldb, int ldc,
             long long sA, long long sB, long long sC, int sBias)
{
  __shared__ __align__(16) unsigned short lA[64 * 64];
  __shared__ __align__(16) unsigned short lB[128 * 64];

  const int t    = blockIdx.z;
  const int row0 = blockIdx.y * 64;
  const int col0 = blockIdx.x * 128;

  const float*          Af = (const float*)Av + (size_t)t * sA;
  const unsigned short* Ab = (const unsigned short*)Av + (size_t)t * sA;
  const unsigned short* Bt = Btv + (size_t)t * sB;
  unsigned short*       C  = Cv + (size_t)t * sC;

  const int tid  = threadIdx.x;
  const int lane = tid & 63;
  const int wave = tid >> 6;       // 0..3
  const int wr   = wave >> 1;      // 0..1 (row half)
  const int wc   = wave & 1;       // 0..1 (col half)
  const int fr   = lane & 15;
  const int fk   = (lane >> 4) << 3;

  const int arow = tid >> 2;           // 0..63
  const int acol = (tid & 3) << 4;     // 0,16,32,48
  const int brow = tid >> 1;           // 0..127
  const int bcol = (tid & 1) << 5;     // 0,32

  f32x4 acc[2][4] = {};

  for (int k0 = 0; k0 < K; k0 += 64) {
    __syncthreads();
    if constexpr (AFP32) {
      const float* a = Af + (size_t)(row0 + arow) * lda + k0 + acol;
      #pragma unroll
      for (int j = 0; j < 2; ++j) {
        float4 f0 = *(const float4*)(a + j * 8);
        float4 f1 = *(const float4*)(a + j * 8 + 4);
        uint4 w;
        w.x = (unsigned)f2bf(f0.x) | ((unsigned)f2bf(f0.y) << 16);
        w.y = (unsigned)f2bf(f0.z) | ((unsigned)f2bf(f0.w) << 16);
        w.z = (unsigned)f2bf(f1.x) | ((unsigned)f2bf(f1.y) << 16);
        w.w = (unsigned)f2bf(f1.z) | ((unsigned)f2bf(f1.w) << 16);
        *(uint4*)&lA[swz(arow, acol + j * 8)] = w;
      }
    } else {
      const unsigned short* a = Ab + (size_t)(row0 + arow) * lda + k0 + acol;
      #pragma unroll
      for (int j = 0; j < 2; ++j)
        *(uint4*)&lA[swz(arow, acol + j * 8)] = *(const uint4*)(a + j * 8);
    }
    {
      const unsigned short* b = Bt + (size_t)(col0 + brow) * ldb + k0 + bcol;
      #pragma unroll
      for (int j = 0; j < 4; ++j)
        *(uint4*)&lB[swz(brow, bcol + j * 8)] = *(const uint4*)(b + j * 8);
    }
    __syncthreads();

    #pragma unroll
    for (int kk = 0; kk < 2; ++kk) {
      short8 af[2], bfr[4];
      #pragma unroll
      for (int mi = 0; mi < 2; ++mi)
        af[mi] = *(const short8*)&lA[swz(wr * 32 + mi * 16 + fr, kk * 32 + fk)];
      #pragma unroll
      for (int ni = 0; ni < 4; ++ni)
        bfr[ni] = *(const short8*)&lB[swz(wc * 64 + ni * 16 + fr, kk * 32 + fk)];
      #pragma unroll
      for (int mi = 0; mi < 2; ++mi) {
        #pragma unroll
        for (int ni = 0; ni < 4; ++ni)
          acc[mi][ni] = __builtin_amdgcn_mfma_f32_16x16x32_bf16(
              af[mi], bfr[ni], acc[mi][ni], 0, 0, 0);
      }
    }
  }

  const float* bias = nullptr;
  if constexpr (BIAS_MODE != 0) bias = biasv + (size_t)t * sBias;
  const int erow = (lane >> 4) << 2;
  #pragma unroll
  for (int mi = 0; mi < 2; ++mi) {
    #pragma unroll
    for (int ni = 0; ni < 4; ++ni) {
      #pragma unroll
      for (int j = 0; j < 4; ++j) {
        int row = row0 + wr * 32 + mi * 16 + erow + j;
        int col = col0 + wc * 64 + ni * 16 + fr;
        float v = acc[mi][ni][j];
        if constexpr (BIAS_MODE == 1) v += bias[row];
        if constexpr (BIAS_MODE == 2) v += bias[col];
        if constexpr (RELU) v = fmaxf(v, 0.0f);
        C[(size_t)row * ldc + col] = f2bf(v);
      }
    }
  }
}

// ---------------- head: logits = feat @ W_lin^T + b, then log_softmax -----
// block = 256 threads = 8 row-groups x 32 cols; 16 rows per block (2/thread).
__global__ __launch_bounds__(256)
void head_kernel(const unsigned short* __restrict__ h2,
                 const unsigned short* __restrict__ Wl,
                 const float* __restrict__ blin,
                 float* __restrict__ out)
{
  const int tid = threadIdx.x;
  const int c   = tid & 31;
  const int rg  = tid >> 5;             // 0..7
  const int i0  = blockIdx.x * 16;
  const int r0  = i0 + rg;
  const int r1  = i0 + rg + 8;
  float acc0 = 0.f, acc1 = 0.f;
  #pragma unroll
  for (int t = 0; t < 3; ++t) {
    const unsigned short* x0 = h2 + (size_t)t * 2097152 + (size_t)r0 * 512;
    const unsigned short* x1 = h2 + (size_t)t * 2097152 + (size_t)r1 * 512;
    const unsigned short* wt = Wl + (size_t)c * 1536 + t * 512;
    #pragma unroll 4
    for (int k = 0; k < 512; k += 8) {
      uint4 wv = *(const uint4*)(wt + k);
      uint4 a0 = *(const uint4*)(x0 + k);
      uint4 a1 = *(const uint4*)(x1 + k);
      const unsigned* wu = (const unsigned*)&wv;
      const unsigned* u0 = (const unsigned*)&a0;
      const unsigned* u1 = (const unsigned*)&a1;
      #pragma unroll
      for (int q = 0; q < 4; ++q) {
        float wl = bflo(wu[q]), wh = bfhi(wu[q]);
        acc0 += bflo(u0[q]) * wl + bfhi(u0[q]) * wh;
        acc1 += bflo(u1[q]) * wl + bfhi(u1[q]) * wh;
      }
    }
  }
  acc0 += blin[c]; acc1 += blin[c];
  float m0 = acc0, m1 = acc1;
  #pragma unroll
  for (int s = 16; s; s >>= 1) {
    m0 = fmaxf(m0, __shfl_xor(m0, s, 32));
    m1 = fmaxf(m1, __shfl_xor(m1, s, 32));
  }
  float e0 = expf(acc0 - m0), e1 = expf(acc1 - m1);
  #pragma unroll
  for (int s = 16; s; s >>= 1) {
    e0 += __shfl_xor(e0, s, 32);
    e1 += __shfl_xor(e1, s, 32);
  }
  out[(size_t)r0 * 32 + c] = acc0 - m0 - logf(e0);
  out[(size_t)r1 * 32 + c] = acc1 - m1 - logf(e1);
}

extern "C" void kernel_launch(void* const* d_in, const int* in_sizes, int n_in,
                              void* d_out, int out_size, void* d_ws, size_t ws_size,
                              hipStream_t stream)
{
  const float* x      = (const float*)d_in[0];
  const float* adj    = (const float*)d_in[1];
  // d_in[2] = node_type_mask (unused: contiguous equal blocks by construction)
  const float* W_conv = (const float*)d_in[3];
  const float* b_conv = (const float*)d_in[4];
  const float* W_sage = (const float*)d_in[5];
  const float* b_sage = (const float*)d_in[6];
  const float* W_lin  = (const float*)d_in[7];
  const float* b_lin  = (const float*)d_in[8];
  float* out = (float*)d_out;

  // workspace layout (bf16 elems); m reuses xbf, h2 reuses ht (disjoint per kernel)
  unsigned short* ws  = (unsigned short*)d_ws;
  unsigned short* xbf = ws;                       // 6291456  (x bf16; later m)
  unsigned short* Wc  = xbf + 6291456;            // 786432
  unsigned short* Wsg = Wc + 786432;              // 786432
  unsigned short* Wl  = Wsg + 786432;             // 49152
  unsigned short* ht  = Wl + 49152;               // 6291456  (h^T; later h2)
  unsigned short* m_  = xbf;
  unsigned short* h2  = ht;

  cast_kernel<<<3072, 256, 0, stream>>>(x, xbf, 786432);
  cast_kernel<<<384, 256, 0, stream>>>(W_conv, Wc, 98304);
  cast_kernel<<<384, 256, 0, stream>>>(W_sage, Wsg, 98304);
  cast_kernel<<<24, 256, 0, stream>>>(W_lin, Wl, 6144);

  // GEMM1: h^T[t] = relu(W_conv[t] @ xs[t]^T + b_conv[t])  [512 x 4096]
  gemm_bt<0, 1, 1><<<dim3(32, 8, 3), 256, 0, stream>>>(
      Wc, xbf, ht, b_conv, 512, 512, 512, 4096,
      262144LL, 2097152LL, 2097152LL, 512);

  // GEMM2 (spmm): m[t] = adj_b[t] @ h[t]  [4096 x 512], A = fp32 adj
  gemm_bt<1, 0, 0><<<dim3(4, 64, 3), 256, 0, stream>>>(
      adj, ht, m_, nullptr, 4096, 12288, 4096, 512,
      4096LL, 2097152LL, 2097152LL, 0);

  // GEMM3: h2[t] = relu(m[t] @ W_sage[t]^T + b_sage[t])  [4096 x 512]
  gemm_bt<0, 2, 1><<<dim3(4, 64, 3), 256, 0, stream>>>(
      m_, Wsg, h2, b_sage, 512, 512, 512, 512,
      2097152LL, 262144LL, 2097152LL, 512);

  // head: logits + log_softmax  [4096 x 32]
  head_kernel<<<256, 256, 0, stream>>>(h2, Wl, b_lin, out);
}

// Round 2
// 249.322 us; speedup vs baseline: 1.1274x; 1.1274x over previous
//
#include <hip/hip_runtime.h>

typedef __attribute__((ext_vector_type(8))) short short8;
typedef __attribute__((ext_vector_type(4))) float f32x4;

__device__ __forceinline__ unsigned short f2bf(float f) {
  union { float f; unsigned u; } v; v.f = f;
  unsigned u = v.u + 0x7fffu + ((v.u >> 16) & 1u);
  return (unsigned short)(u >> 16);
}
__device__ __forceinline__ float bflo(unsigned u) {
  union { unsigned u; float f; } v; v.u = u << 16; return v.f;
}
__device__ __forceinline__ float bfhi(unsigned u) {
  union { unsigned u; float f; } v; v.u = u & 0xffff0000u; return v.f;
}
// v_cvt_pk_bf16_f32: 2 fp32 -> packed 2 bf16 (RNE), 1 inst (no builtin on gfx950)
__device__ __forceinline__ unsigned cvtpk(float lo, float hi) {
  unsigned r;
  asm("v_cvt_pk_bf16_f32 %0, %1, %2" : "=v"(r) : "v"(lo), "v"(hi));
  return r;
}
// async global->LDS, 16B per lane; LDS dest = wave-uniform base + lane*16
typedef unsigned int u32;
typedef u32 __attribute__((address_space(3)))* lds_u32p;
typedef const u32 __attribute__((address_space(1)))* glob_u32p;
__device__ __forceinline__ void glds16(const unsigned short* g, unsigned short* l) {
  __builtin_amdgcn_global_load_lds((glob_u32p)(const void*)g, (lds_u32p)(void*)l,
                                   16, 0, 0);
}

// ---------------- fp32 -> bf16 cast (weights only) ------------------------
__global__ __launch_bounds__(256) void cast_kernel(
    const float* __restrict__ in, unsigned short* __restrict__ out, int n8) {
  int i = blockIdx.x * 256 + threadIdx.x;
  if (i >= n8) return;
  const float* p = in + (size_t)i * 8;
  float4 f0 = *(const float4*)p;
  float4 f1 = *(const float4*)(p + 4);
  uint4 w;
  w.x = cvtpk(f0.x, f0.y); w.y = cvtpk(f0.z, f0.w);
  w.z = cvtpk(f1.x, f1.y); w.w = cvtpk(f1.z, f1.w);
  *(uint4*)(out + (size_t)i * 8) = w;
}

// ---------------- gemm_bt 128x128xBK64, m97 structure ---------------------
// C[MxN](bf16) = op(A[MxK] @ Bt[NxK]^T).  4 waves (2x2), 64x64 per wave.
// bf16 operands: global_load_lds_dwordx4, T2 swizzle via pre-swizzled source.
// fp32 operands (A_F32/B_F32): reg-staged, v_cvt_pk_bf16_f32, swizzled write.
// All LDS tiles use layout elem(row,col) at [row*64 + (col ^ ((row&7)<<3))].
// BIAS_MODE: 0 none, 1 per-row, 2 per-col.
template<int A_F32, int B_F32, int BIAS_MODE, int RELU>
__global__ __launch_bounds__(256)
void gemm128(const void* __restrict__ Av, const void* __restrict__ Btv,
             unsigned short* __restrict__ Cv, const float* __restrict__ biasv,
             int K, int lda, int ldb, int ldc,
             long long sA, long long sB, long long sC, int sBias)
{
  __shared__ __align__(16) unsigned short lA[128 * 64];
  __shared__ __align__(16) unsigned short lB[128 * 64];

  // bijective XCD swizzle (grid is 384 = 48/XCD): neighbors share A-panels
  int gx = gridDim.x, gy = gridDim.y;
  int bid = blockIdx.x + gx * (blockIdx.y + gy * blockIdx.z);
  int nwg = gx * gy * gridDim.z;
  int s   = (bid & 7) * (nwg >> 3) + (bid >> 3);
  int bx  = s % gx;
  int by  = (s / gx) % gy;
  int t   = s / (gx * gy);

  const int row0 = by * 128;
  const int col0 = bx * 128;

  const float*          Af = (const float*)Av + (size_t)t * sA;
  const unsigned short* Ab = (const unsigned short*)Av + (size_t)t * sA;
  const float*          Bf = (const float*)Btv + (size_t)t * sB;
  const unsigned short* Bb = (const unsigned short*)Btv + (size_t)t * sB;
  unsigned short*       C  = Cv + (size_t)t * sC;

  const int tid  = threadIdx.x;
  const int lane = tid & 63;
  const int wave = tid >> 6;       // 0..3
  const int wr   = wave >> 1;      // 0..1
  const int wc   = wave & 1;       // 0..1
  const int fr   = lane & 15;
  const int fk   = (lane >> 4) << 3;

  // glds mapping: seg = issue*4+wave covers rows seg*8..seg*8+7; lane -> 16B
  const int grow = lane >> 3;                 // +row within seg
  const int gcol = ((lane & 7) << 3);         // stored col
  // pre-swizzled source col so that linear LDS dest == swizzled layout
  // (rule #21: inverse-swz source + swz read; XOR is an involution)
  const int srow = tid >> 1;                  // cvt-stage row 0..127
  const int scol = (tid & 1) << 5;            // 0 or 32

  f32x4 acc[4][4] = {};

  for (int k0 = 0; k0 < K; k0 += 64) {
    __syncthreads();
    // ---- stage A ----
    if constexpr (A_F32) {
      const float* p = Af + (size_t)(row0 + srow) * lda + k0 + scol;
      float4 f[8];
      #pragma unroll
      for (int j = 0; j < 8; ++j) f[j] = *(const float4*)(p + j * 4);
      #pragma unroll
      for (int j = 0; j < 4; ++j) {
        uint4 w;
        w.x = cvtpk(f[2*j].x,   f[2*j].y);
        w.y = cvtpk(f[2*j].z,   f[2*j].w);
        w.z = cvtpk(f[2*j+1].x, f[2*j+1].y);
        w.w = cvtpk(f[2*j+1].z, f[2*j+1].w);
        int c = (scol + j * 8) ^ ((srow & 7) << 3);
        *(uint4*)&lA[srow * 64 + c] = w;
      }
    } else {
      #pragma unroll
      for (int i = 0; i < 4; ++i) {
        int seg = i * 4 + wave;
        int r   = seg * 8 + grow;
        int c   = gcol ^ ((r & 7) << 3);
        glds16(Ab + (size_t)(row0 + r) * lda + k0 + c, &lA[seg * 512]);
      }
    }
    // ---- stage B ----
    if constexpr (B_F32) {
      const float* p = Bf + (size_t)(col0 + srow) * ldb + k0 + scol;
      float4 f[8];
      #pragma unroll
      for (int j = 0; j < 8; ++j) f[j] = *(const float4*)(p + j * 4);
      #pragma unroll
      for (int j = 0; j < 4; ++j) {
        uint4 w;
        w.x = cvtpk(f[2*j].x,   f[2*j].y);
        w.y = cvtpk(f[2*j].z,   f[2*j].w);
        w.z = cvtpk(f[2*j+1].x, f[2*j+1].y);
        w.w = cvtpk(f[2*j+1].z, f[2*j+1].w);
        int c = (scol + j * 8) ^ ((srow & 7) << 3);
        *(uint4*)&lB[srow * 64 + c] = w;
      }
    } else {
      #pragma unroll
      for (int i = 0; i < 4; ++i) {
        int seg = i * 4 + wave;
        int r   = seg * 8 + grow;
        int c   = gcol ^ ((r & 7) << 3);
        glds16(Bb + (size_t)(col0 + r) * ldb + k0 + c, &lB[seg * 512]);
      }
    }
    __syncthreads();  // compiler drains vmcnt+lgkmcnt here

    #pragma unroll
    for (int kk = 0; kk < 2; ++kk) {
      short8 af[4], bf_[4];
      #pragma unroll
      for (int mi = 0; mi < 4; ++mi) {
        int r = wr * 64 + mi * 16 + fr;
        int c = (kk * 32 + fk) ^ ((r & 7) << 3);
        af[mi] = *(const short8*)&lA[r * 64 + c];
      }
      #pragma unroll
      for (int ni = 0; ni < 4; ++ni) {
        int r = wc * 64 + ni * 16 + fr;
        int c = (kk * 32 + fk) ^ ((r & 7) << 3);
        bf_[ni] = *(const short8*)&lB[r * 64 + c];
      }
      #pragma unroll
      for (int mi = 0; mi < 4; ++mi)
        #pragma unroll
        for (int ni = 0; ni < 4; ++ni)
          acc[mi][ni] = __builtin_amdgcn_mfma_f32_16x16x32_bf16(
              af[mi], bf_[ni], acc[mi][ni], 0, 0, 0);
    }
  }

  const float* bias = nullptr;
  if constexpr (BIAS_MODE != 0) bias = biasv + (size_t)t * sBias;
  const int erow = (lane >> 4) << 2;
  #pragma unroll
  for (int mi = 0; mi < 4; ++mi) {
    #pragma unroll
    for (int ni = 0; ni < 4; ++ni) {
      #pragma unroll
      for (int j = 0; j < 4; ++j) {
        int row = row0 + wr * 64 + mi * 16 + erow + j;
        int col = col0 + wc * 64 + ni * 16 + fr;
        float v = acc[mi][ni][j];
        if constexpr (BIAS_MODE == 1) v += bias[row];
        if constexpr (BIAS_MODE == 2) v += bias[col];
        if constexpr (RELU) v = fmaxf(v, 0.0f);
        C[(size_t)row * ldc + col] = f2bf(v);
      }
    }
  }
}

// ---------------- head: logits = feat @ W_lin^T + b, then log_softmax -----
__global__ __launch_bounds__(256)
void head_kernel(const unsigned short* __restrict__ h2,
                 const unsigned short* __restrict__ Wl,
                 const float* __restrict__ blin,
                 float* __restrict__ out)
{
  const int tid = threadIdx.x;
  const int c   = tid & 31;
  const int rg  = tid >> 5;
  const int i0  = blockIdx.x * 16;
  const int r0  = i0 + rg;
  const int r1  = i0 + rg + 8;
  float acc0 = 0.f, acc1 = 0.f;
  #pragma unroll
  for (int t = 0; t < 3; ++t) {
    const unsigned short* x0 = h2 + (size_t)t * 2097152 + (size_t)r0 * 512;
    const unsigned short* x1 = h2 + (size_t)t * 2097152 + (size_t)r1 * 512;
    const unsigned short* wt = Wl + (size_t)c * 1536 + t * 512;
    #pragma unroll 4
    for (int k = 0; k < 512; k += 8) {
      uint4 wv = *(const uint4*)(wt + k);
      uint4 a0 = *(const uint4*)(x0 + k);
      uint4 a1 = *(const uint4*)(x1 + k);
      const unsigned* wu = (const unsigned*)&wv;
      const unsigned* u0 = (const unsigned*)&a0;
      const unsigned* u1 = (const unsigned*)&a1;
      #pragma unroll
      for (int q = 0; q < 4; ++q) {
        float wl = bflo(wu[q]), wh = bfhi(wu[q]);
        acc0 += bflo(u0[q]) * wl + bfhi(u0[q]) * wh;
        acc1 += bflo(u1[q]) * wl + bfhi(u1[q]) * wh;
      }
    }
  }
  acc0 += blin[c]; acc1 += blin[c];
  float m0 = acc0, m1 = acc1;
  #pragma unroll
  for (int s = 16; s; s >>= 1) {
    m0 = fmaxf(m0, __shfl_xor(m0, s, 32));
    m1 = fmaxf(m1, __shfl_xor(m1, s, 32));
  }
  float e0 = expf(acc0 - m0), e1 = expf(acc1 - m1);
  #pragma unroll
  for (int s = 16; s; s >>= 1) {
    e0 += __shfl_xor(e0, s, 32);
    e1 += __shfl_xor(e1, s, 32);
  }
  out[(size_t)r0 * 32 + c] = acc0 - m0 - logf(e0);
  out[(size_t)r1 * 32 + c] = acc1 - m1 - logf(e1);
}

extern "C" void kernel_launch(void* const* d_in, const int* in_sizes, int n_in,
                              void* d_out, int out_size, void* d_ws, size_t ws_size,
                              hipStream_t stream)
{
  const float* x      = (const float*)d_in[0];
  const float* adj    = (const float*)d_in[1];
  // d_in[2] = node_type_mask (unused: contiguous equal blocks by construction)
  const float* W_conv = (const float*)d_in[3];
  const float* b_conv = (const float*)d_in[4];
  const float* W_sage = (const float*)d_in[5];
  const float* b_sage = (const float*)d_in[6];
  const float* W_lin  = (const float*)d_in[7];
  const float* b_lin  = (const float*)d_in[8];
  float* out = (float*)d_out;

  // workspace (bf16 elems). h2 reuses ht (ht dead after spmm; gemm3 does not
  // read ht).  m_ must NOT alias ht (spmm reads ht while writing m_).
  unsigned short* ws  = (unsigned short*)d_ws;
  unsigned short* Wc  = ws;                   // 786432
  unsigned short* Wsg = Wc + 786432;          // 786432
  unsigned short* Wl  = Wsg + 786432;         // 49152
  unsigned short* ht  = Wl + 49152;           // 2097152*3 (h^T; later h2)
  unsigned short* m_  = ht + 6291456;         // 2097152*3
  unsigned short* h2  = ht;

  cast_kernel<<<384, 256, 0, stream>>>(W_conv, Wc, 98304);
  cast_kernel<<<384, 256, 0, stream>>>(W_sage, Wsg, 98304);
  cast_kernel<<<24, 256, 0, stream>>>(W_lin, Wl, 6144);

  // GEMM1: ht[t] = relu(W_conv[t] @ xs[t]^T + b_conv[t])  [512 x 4096]
  //   A = Wc bf16 (glds), Bt = x fp32 (cvt-staged), bias per-row
  gemm128<0, 1, 1, 1><<<dim3(32, 4, 3), 256, 0, stream>>>(
      Wc, x, ht, b_conv, 512, 512, 512, 4096,
      262144LL, 2097152LL, 2097152LL, 512);

  // GEMM2 (spmm): m[t] = adj_b[t] @ h[t]  [4096 x 512]
  //   A = adj fp32 (cvt-staged, lda=12288, per-t col offset), Bt = ht (glds)
  gemm128<1, 0, 0, 0><<<dim3(4, 32, 3), 256, 0, stream>>>(
      adj, ht, m_, nullptr, 4096, 12288, 4096, 512,
      4096LL, 2097152LL, 2097152LL, 0);

  // GEMM3: h2[t] = relu(m[t] @ W_sage[t]^T + b_sage[t])  [4096 x 512]
  gemm128<0, 0, 2, 1><<<dim3(4, 32, 3), 256, 0, stream>>>(
      m_, Wsg, h2, b_sage, 512, 512, 512, 512,
      2097152LL, 262144LL, 2097152LL, 512);

  head_kernel<<<256, 256, 0, stream>>>(h2, Wl, b_lin, out);
}